// Round 9
// baseline (577.213 us; speedup 1.0000x reference)
//
#include <hip/hip_runtime.h>
#include <math.h>

#define NN 100000
#define NE 200000
#define HD 128
#define CAPN 4096
#define CAPS 4096
#define CAPT 4096
#define NGROUP 21
#define AP 136             // bf16 LDS row pitch (shorts)
#define NTHR 256

typedef short bf16x8 __attribute__((ext_vector_type(8)));
typedef float f32x4 __attribute__((ext_vector_type(4)));

// workspace byte offsets; [0, MEMSET_BYTES) zeroed each launch
#define OFF_CNT    0           // ncnt[21]
#define OFF_SCNT   128         // 15 ints
#define OFF_TCNT   256         // 18 ints (was 192: overlapped zcntN — fixed)
#define OFF_ZCNTN  512         // NN*8 ints: dead-edge counts per (dst, src gate)
#define MEMSET_BYTES 3200512
#define OFF_MSGN   3200512     // NN*128 f32 (zeroed by prep_b, node-indexed)
#define OFF_HSTYPE 54400512    // 6*128 f32
#define OFF_HSW1   54403584    // 3*6*128 f32
#define OFF_ZTAB   54412800    // 3*6*128 f32
#define OFF_WBMLP  54422016    // 3*3*16384 bf16 swizzled B-frags
#define OFF_WBIH   54716928    // 3*49152 bf16 swizzled B-frags
#define OFF_NLIST  55011840    // 21*4096 ints
#define OFF_SSRC   55355904    // 15*4096 ints (stale: src node)
#define OFF_SDST   55601664    // 15*4096 ints (stale: dst node)
#define OFF_TSRC   55847424    // 18*4096 ints (tight: src node)
#define OFF_TDST   56142336    // 18*4096 ints (tight: dst node)

#define SWTOT (3 * 3 * 16384 + 3 * 49152)

__device__ __forceinline__ int gi_of(int g) {
    return (g == 3) ? 0 : (g == 2) ? 1 : (g == 5) ? 2 : -1;
}

__device__ __forceinline__ unsigned short f2bf(float f) {
    unsigned int u = __float_as_uint(f);
    u += 0x7FFF + ((u >> 16) & 1);   // RNE
    return (unsigned short)(u >> 16);
}

// ---------------------------------------------------------------------------
// 3-layer MFMA MLP over the staged bf16 tile SH (wave-local 16-row bands) +
// fp32 atomic scatter into node-indexed msgN.  No block barriers inside.
// ---------------------------------------------------------------------------
__device__ __forceinline__ void mlp3_scatter(
    const unsigned short* __restrict__ WB, const float* hsw,
    const float* __restrict__ b1g, const float* __restrict__ b2g,
    const float* __restrict__ b3g, unsigned short* SH, int nv,
    int sg, int sd, float* __restrict__ msgN,
    int rbase, int ln, int lc, int quad) {
    float b1v[8], b2v[8], b3v[8];
#pragma unroll
    for (int nt = 0; nt < 8; nt++) {
        b1v[nt] = b1g[nt * 16 + lc];
        b2v[nt] = b2g[nt * 16 + lc];
        b3v[nt] = b3g[nt * 16 + lc];
    }
    // layer 1: relu(hsW1[gate_src] + hf@W1bot + b1), in-place
    {
        bf16x8 af[4];
#pragma unroll
        for (int kc = 0; kc < 4; kc++)
            af[kc] = *(bf16x8*)&SH[(rbase + lc) * AP + kc * 32 + quad * 8];
        for (int nt = 0; nt < 8; nt++) {
            f32x4 acc = {0.f, 0.f, 0.f, 0.f};
#pragma unroll
            for (int kc = 0; kc < 4; kc++) {
                bf16x8 bf = *(const bf16x8*)&WB[((nt * 4 + kc) * 64 + ln) * 8];
                acc = __builtin_amdgcn_mfma_f32_16x16x32_bf16(af[kc], bf, acc, 0, 0, 0);
            }
#pragma unroll
            for (int r = 0; r < 4; r++) {
                int row = rbase + quad * 4 + r;
                int sgr = __shfl(sg, quad * 4 + r);
                float v = acc[r] + hsw[sgr * 132 + nt * 16 + lc] + b1v[nt];
                SH[row * AP + nt * 16 + lc] = f2bf(fmaxf(v, 0.f));
            }
        }
    }
    // layer 2
    {
        bf16x8 af[4];
#pragma unroll
        for (int kc = 0; kc < 4; kc++)
            af[kc] = *(bf16x8*)&SH[(rbase + lc) * AP + kc * 32 + quad * 8];
        for (int nt = 0; nt < 8; nt++) {
            f32x4 acc = {0.f, 0.f, 0.f, 0.f};
#pragma unroll
            for (int kc = 0; kc < 4; kc++) {
                bf16x8 bf = *(const bf16x8*)&WB[16384 + ((nt * 4 + kc) * 64 + ln) * 8];
                acc = __builtin_amdgcn_mfma_f32_16x16x32_bf16(af[kc], bf, acc, 0, 0, 0);
            }
#pragma unroll
            for (int r = 0; r < 4; r++) {
                int row = rbase + quad * 4 + r;
                SH[row * AP + nt * 16 + lc] = f2bf(fmaxf(acc[r] + b2v[nt], 0.f));
            }
        }
    }
    // layer 3 + scatter-add
    {
        bf16x8 af[4];
#pragma unroll
        for (int kc = 0; kc < 4; kc++)
            af[kc] = *(bf16x8*)&SH[(rbase + lc) * AP + kc * 32 + quad * 8];
        for (int nt = 0; nt < 8; nt++) {
            f32x4 acc = {0.f, 0.f, 0.f, 0.f};
#pragma unroll
            for (int kc = 0; kc < 4; kc++) {
                bf16x8 bf = *(const bf16x8*)&WB[2 * 16384 + ((nt * 4 + kc) * 64 + ln) * 8];
                acc = __builtin_amdgcn_mfma_f32_16x16x32_bf16(af[kc], bf, acc, 0, 0, 0);
            }
#pragma unroll
            for (int r = 0; r < 4; r++) {
                int row = rbase + quad * 4 + r;
                if (row < nv) {
                    int sdr = __shfl(sd, quad * 4 + r);
                    atomicAdd(&msgN[(size_t)sdr * HD + nt * 16 + lc], acc[r] + b3v[nt]);
                }
            }
        }
    }
}

// ---------------------------------------------------------------------------
// prep_a (small): block 0 -> hs_type + hsW1; blocks 1..18 -> ztab;
// blocks 19+ -> weight swizzle.  Tables computed ONCE (round-8 regression:
// 1005 blocks each redoing the hs table cost ~46 µs of L2 traffic).
// ---------------------------------------------------------------------------
__global__ __launch_bounds__(NTHR) void prep_a_kernel(
    const float* __restrict__ Ws, const float* __restrict__ Wt,
    const float* __restrict__ hs_W, const float* __restrict__ hs_b,
    const float* __restrict__ w1, const float* __restrict__ b1,
    const float* __restrict__ w2, const float* __restrict__ b2,
    const float* __restrict__ w3, const float* __restrict__ b3,
    const float* __restrict__ wih,
    float* __restrict__ hs_type, float* __restrict__ hsW1,
    float* __restrict__ ztab,
    unsigned short* __restrict__ wbmlp, unsigned short* __restrict__ wbih) {
    __shared__ float lht[6 * HD];
    __shared__ float s0[HD], s1[HD], s2[HD];
    const int bid = blockIdx.x, tid = threadIdx.x;

    if (bid == 0) {
        for (int idx = tid; idx < 6 * HD; idx += NTHR) {
            int t = idx >> 7, c = idx & 127;
            float acc = hs_b[c];
            for (int k = 0; k < HD; k++) acc = fmaf(Ws[t * HD + k], hs_W[k * HD + c], acc);
            for (int k = 0; k < HD; k++) acc = fmaf(Wt[t * HD + k], hs_W[(HD + k) * HD + c], acc);
            lht[idx] = acc;
            hs_type[idx] = acc;
        }
        __syncthreads();
        for (int idx = tid; idx < 3 * 6 * HD; idx += NTHR) {
            int gi = idx / (6 * HD);
            int t = (idx >> 7) % 6;
            int c = idx & 127;
            const float* w = w1 + gi * (2 * HD * HD);  // top half rows 0..127
            float acc = 0.f;
            for (int k = 0; k < HD; k++) acc = fmaf(lht[t * HD + k], w[k * HD + c], acc);
            hsW1[idx] = acc;
        }
    } else if (bid <= 18) {
        // ztab[gi][t] = MLP_gi([hs_type[t], 0])  (dead-edge message, fp32)
        int gi = (bid - 1) / 6, t = (bid - 1) % 6;
        int c = tid;
        if (c < HD) {
            float acc = hs_b[c];
            for (int k = 0; k < HD; k++) acc = fmaf(Ws[t * HD + k], hs_W[k * HD + c], acc);
            for (int k = 0; k < HD; k++) acc = fmaf(Wt[t * HD + k], hs_W[(HD + k) * HD + c], acc);
            s0[c] = acc;
        }
        __syncthreads();
        if (c < HD) {
            const float* w = w1 + gi * (2 * HD * HD);
            float acc = b1[gi * HD + c];
            for (int k = 0; k < HD; k++) acc = fmaf(s0[k], w[k * HD + c], acc);
            s1[c] = fmaxf(acc, 0.f);
        }
        __syncthreads();
        if (c < HD) {
            const float* w = w2 + gi * (HD * HD);
            float acc = b2[gi * HD + c];
            for (int k = 0; k < HD; k++) acc = fmaf(s1[k], w[k * HD + c], acc);
            s2[c] = fmaxf(acc, 0.f);
        }
        __syncthreads();
        if (c < HD) {
            const float* w = w3 + gi * (HD * HD);
            float acc = b3[gi * HD + c];
            for (int k = 0; k < HD; k++) acc = fmaf(s2[k], w[k * HD + c], acc);
            ztab[(gi * 6 + t) * HD + c] = acc;
        }
    } else {
        const int nb = gridDim.x - 19;
        const int wb = bid - 19;
        for (int id = wb * NTHR + tid; id < SWTOT; id += nb * NTHR) {
            if (id < 3 * 3 * 16384) {
                int gi = id / 49152;
                int rem = id % 49152;
                int layer = rem / 16384;
                int e = rem % 16384;
                int k = e >> 7, n = e & 127;
                float v;
                if (layer == 0)      v = w1[gi * (2 * HD * HD) + (HD + k) * HD + n];
                else if (layer == 1) v = w2[gi * (HD * HD) + k * HD + n];
                else                 v = w3[gi * (HD * HD) + k * HD + n];
                int nt = n >> 4, kc = k >> 5, kq = (k >> 3) & 3, j = k & 7;
                int L = (kq << 4) | (n & 15);
                wbmlp[(size_t)(gi * 3 + layer) * 16384 + ((nt * 4 + kc) * 64 + L) * 8 + j] = f2bf(v);
            } else {
                int id2 = id - 3 * 3 * 16384;
                int gi = id2 / 49152;
                int e = id2 % 49152;
                int k = e / 384, n = e % 384;             // B[k][n] = wih[n][k]
                float v = wih[gi * (384 * HD) + n * HD + k];
                int nt = n >> 4, kc = k >> 5, kq = (k >> 3) & 3, j = k & 7;
                int L = (kq << 4) | (n & 15);
                wbih[(size_t)gi * 49152 + ((nt * 4 + kc) * 64 + L) * 8 + j] = f2bf(v);
            }
        }
    }
}

// ---------------------------------------------------------------------------
// prep_b (big, streaming): out init (hs gather from global hs_type — written
// by the PREVIOUS dispatch, so no race) + msgN zero + group_nodes +
// group_edges (tight/stale/dead classification).
// ---------------------------------------------------------------------------
__global__ __launch_bounds__(NTHR) void prep_b_kernel(
    const int* __restrict__ gate, const int* __restrict__ lvl,
    const int* __restrict__ ei, const float* __restrict__ hs_type,
    float* __restrict__ out, float* __restrict__ msgN,
    int* __restrict__ ncnt, int* __restrict__ nlist,
    int* __restrict__ scnt, int* __restrict__ ssrc, int* __restrict__ sdst,
    int* __restrict__ tcnt, int* __restrict__ tsrc, int* __restrict__ tdst,
    int* __restrict__ zcntN) {
    __shared__ int lcnt[40], lbase[40];
    const int bid = blockIdx.x, tid = threadIdx.x;
    const int stride = gridDim.x * NTHR;

    // out init: hs scatter + hf zero (102 MB)
    {
        const float4* ht4 = (const float4*)hs_type;
        float4* o4 = (float4*)out;
        for (int idx = bid * NTHR + tid; idx < NN * 32; idx += stride) {
            int i = idx >> 5, q = idx & 31;
            o4[idx] = ht4[gate[i] * 32 + q];
            o4[(size_t)NN * 32 + idx] = make_float4(0.f, 0.f, 0.f, 0.f);
        }
    }
    // msgN zero (51 MB)
    {
        float4* m4 = (float4*)msgN;
        for (int idx = bid * NTHR + tid; idx < NN * 32; idx += stride)
            m4[idx] = make_float4(0.f, 0.f, 0.f, 0.f);
    }
    // group_nodes (LDS-aggregated)
    for (int base = 0; base < NN; base += stride) {
        if (tid < NGROUP) lcnt[tid] = 0;
        __syncthreads();
        int i = base + bid * NTHR + tid;
        int glob = -1, local = 0;
        if (i < NN) {
            int gi = gi_of(gate[i]);
            int l = lvl[i];
            if (gi >= 0 && l >= 1) {
                glob = (l - 1) * 3 + gi;
                local = atomicAdd(&lcnt[glob], 1);
            }
        }
        __syncthreads();
        if (tid < NGROUP) {
            int cc = lcnt[tid];
            lbase[tid] = cc ? atomicAdd(&ncnt[tid], cc) : 0;
        }
        __syncthreads();
        if (glob >= 0) {
            int slot = lbase[glob] + local;
            if (slot < CAPN) nlist[glob * CAPN + slot] = i;
        }
        __syncthreads();
    }
    // group_edges: tight (ld==ls+1) / stale (ld>=ls+2) / dead (count only)
    for (int base = 0; base < NE; base += stride) {
        if (tid < 33) lcnt[tid] = 0;
        __syncthreads();
        int e = base + bid * NTHR + tid;
        int cidx = -1, local = 0, s = 0, dn = 0;
        if (e < NE) {
            int dd = ei[NE + e];
            int gd = gi_of(gate[dd]);
            int ld = lvl[dd];
            if (gd >= 0 && ld >= 1) {
                s = ei[e];
                dn = dd;
                int gs = gate[s], ls = lvl[s];
                bool upd = (gi_of(gs) >= 0) && (ls >= 1) && (ls < ld);
                if (!upd) {
                    atomicAdd(&zcntN[(size_t)dd * 8 + gs], 1);
                } else {
                    int gidx = (ls - 1) * 3 + gd;   // tight: d=ls; stale: d=ls+1
                    cidx = (ld == ls + 1) ? gidx : 18 + gidx;
                    local = atomicAdd(&lcnt[cidx], 1);
                }
            }
        }
        __syncthreads();
        if (tid < 33) {
            int cc = lcnt[tid];
            lbase[tid] = cc ? atomicAdd(tid < 18 ? &tcnt[tid] : &scnt[tid - 18], cc) : 0;
        }
        __syncthreads();
        if (cidx >= 0) {
            int slot = lbase[cidx] + local;
            if (cidx < 18) {
                if (slot < CAPT) { tsrc[cidx * CAPT + slot] = s; tdst[cidx * CAPT + slot] = dn; }
            } else {
                int g = cidx - 18;
                if (slot < CAPS) { ssrc[g * CAPS + slot] = s; sdst[g * CAPS + slot] = dn; }
            }
        }
        __syncthreads();
    }
}

// ---------------------------------------------------------------------------
// level_kernel (dispatch d = 1..7), 576 blocks, three INDEPENDENT roles:
//  [0,192)   gru for level-d nodes          (reads msgN[level d] — complete)
//  [192,384) stale push (ls==d-1, ld>=d+1): reads hfout[src] (written <= d-1),
//            writes msgN[level >= d+1]      (disjoint from gru reads)
//  [384,576) tight push (ls==d, ld==d+1):   RECOMPUTES hf[src] from msgN
//            (read-read vs gru), writes msgN[level d+1]
// No intra-kernel sync or fences; levels chain on dispatch boundaries.
// Tight role runs the 3 GRU weight variants SEQUENTIALLY (3 accumulators at
// a time) to keep the whole kernel's VGPR allocation low.
// ---------------------------------------------------------------------------
__global__ __launch_bounds__(NTHR) void level_kernel(
    int d, const int* __restrict__ gate, float* __restrict__ out,
    const float* __restrict__ hsW1, const float* __restrict__ ztab,
    const unsigned short* __restrict__ wbmlp, const unsigned short* __restrict__ wbih,
    const float* __restrict__ b1, const float* __restrict__ b2,
    const float* __restrict__ b3, const float* __restrict__ bih,
    const float* __restrict__ bhh,
    const int* __restrict__ ncnt, const int* __restrict__ nlist,
    const int* __restrict__ scnt, const int* __restrict__ ssrc,
    const int* __restrict__ sdst,
    const int* __restrict__ tcnt, const int* __restrict__ tsrc,
    const int* __restrict__ tdst,
    const int* __restrict__ zcntN, float* __restrict__ msgN) {
    __shared__ unsigned short SH[64 * AP];
    __shared__ float hsw[6 * 132];
    const int bid = blockIdx.x, tid = threadIdx.x;
    const int ln = tid & 63, wv = tid >> 6;
    const int lc = ln & 15, quad = ln >> 4;
    const int rbase = wv * 16;
    float* hfout = out + (size_t)NN * HD;

    if (bid < 192) {
        // ===== gru role =====
        int gi = bid / 64;
        int tile = (bid % 64) * 64;
        int glob = (d - 1) * 3 + gi;
        int cnt = ncnt[glob]; if (cnt > CAPN) cnt = CAPN;
        if (tile >= cnt) return;
        int nv = min(64, cnt - tile);

        // stage msgN + zcnt*ztab fold -> bf16
        {
            int row = rbase + (ln >> 2), q = ln & 3;
            int nrow = (row < nv) ? nlist[glob * CAPN + tile + row] : -1;
            unsigned int* Mu = (unsigned int*)SH;
            int base = (row * AP + q * 32) >> 1;
            if (nrow >= 0) {
                const f32x4* m4 = (const f32x4*)(msgN + (size_t)nrow * HD + q * 32);
                const int* zc = zcntN + (size_t)nrow * 8;
                const f32x4* zt4 = (const f32x4*)ztab;
                f32x4 acc[8];
#pragma unroll
                for (int i = 0; i < 8; i++) acc[i] = m4[i];
#pragma unroll
                for (int t = 0; t < 6; t++) {
                    int ct = zc[t];
                    if (ct) {
                        float f = (float)ct;
                        const f32x4* z = zt4 + (gi * 6 + t) * 32 + q * 8;
#pragma unroll
                        for (int i = 0; i < 8; i++) {
                            acc[i].x = fmaf(f, z[i].x, acc[i].x);
                            acc[i].y = fmaf(f, z[i].y, acc[i].y);
                            acc[i].z = fmaf(f, z[i].z, acc[i].z);
                            acc[i].w = fmaf(f, z[i].w, acc[i].w);
                        }
                    }
                }
#pragma unroll
                for (int i = 0; i < 8; i++) {
                    Mu[base + i * 2]     = f2bf(acc[i].x) | ((unsigned int)f2bf(acc[i].y) << 16);
                    Mu[base + i * 2 + 1] = f2bf(acc[i].z) | ((unsigned int)f2bf(acc[i].w) << 16);
                }
            } else {
#pragma unroll
                for (int i = 0; i < 16; i++) Mu[base + i] = 0u;
            }
        }
        int nd = -1;
        if (ln < 16) {
            int row = rbase + ln;
            nd = (row < nv) ? nlist[glob * CAPN + tile + row] : -1;
        }

        const unsigned short* WB = wbih + (size_t)gi * 49152;
        bf16x8 af[4];
#pragma unroll
        for (int kc = 0; kc < 4; kc++)
            af[kc] = *(bf16x8*)&SH[(rbase + lc) * AP + kc * 32 + quad * 8];

        for (int nt = 0; nt < 8; nt++) {
            f32x4 aR = {0.f, 0.f, 0.f, 0.f};
            f32x4 aZ = {0.f, 0.f, 0.f, 0.f};
            f32x4 aN = {0.f, 0.f, 0.f, 0.f};
#pragma unroll
            for (int kc = 0; kc < 4; kc++) {
                bf16x8 bR = *(const bf16x8*)&WB[(((nt)      * 4 + kc) * 64 + ln) * 8];
                bf16x8 bZ = *(const bf16x8*)&WB[(((nt + 8)  * 4 + kc) * 64 + ln) * 8];
                bf16x8 bN = *(const bf16x8*)&WB[(((nt + 16) * 4 + kc) * 64 + ln) * 8];
                aR = __builtin_amdgcn_mfma_f32_16x16x32_bf16(af[kc], bR, aR, 0, 0, 0);
                aZ = __builtin_amdgcn_mfma_f32_16x16x32_bf16(af[kc], bZ, aZ, 0, 0, 0);
                aN = __builtin_amdgcn_mfma_f32_16x16x32_bf16(af[kc], bN, aN, 0, 0, 0);
            }
            int c = nt * 16 + lc;
            float biR = bih[gi * 384 + c],       bhR = bhh[gi * 384 + c];
            float biZ = bih[gi * 384 + 128 + c], bhZ = bhh[gi * 384 + 128 + c];
            float biN = bih[gi * 384 + 256 + c], bhN = bhh[gi * 384 + 256 + c];
#pragma unroll
            for (int r = 0; r < 4; r++) {
                int row = rbase + quad * 4 + r;
                int n = __shfl(nd, quad * 4 + r);
                if (n >= 0 && row < nv) {
                    float ir = aR[r] + biR + bhR;
                    float iz = aZ[r] + biZ + bhZ;
                    float inn = aN[r] + biN;
                    float rg = 1.f / (1.f + expf(-ir));
                    float zg = 1.f / (1.f + expf(-iz));
                    float nst = tanhf(inn + rg * bhN);
                    hfout[(size_t)n * HD + c] = (1.f - zg) * nst;
                }
            }
        }
    } else if (bid < 384) {
        // ===== stale push role (edges ls==d-1, ld>=d+1) =====
        if (d < 2 || d > 6) return;
        int b = bid - 192;
        int gi = b / 64;
        int tile = (b % 64) * 64;
        int glob = (d - 2) * 3 + gi;
        int cnt = scnt[glob]; if (cnt > CAPS) cnt = CAPS;
        if (tile >= cnt) return;
        int nv = min(64, cnt - tile);
        const int* es = ssrc + glob * CAPS + tile;
        const int* ed = sdst + glob * CAPS + tile;

        for (int i = tid; i < 6 * 132; i += NTHR) {
            int t = i / 132, c = i % 132;
            hsw[i] = (c < HD) ? hsW1[(gi * 6 + t) * HD + c] : 0.f;
        }
        // stage hf[src] from global (written in dispatch <= d-1)
        {
            int row = rbase + (ln >> 2), q = ln & 3;
            unsigned int* Au = (unsigned int*)SH;
            int base = (row * AP + q * 32) >> 1;
            if (row < nv) {
                int s = es[row];
                const float4* src4 = (const float4*)(hfout + (size_t)s * HD + q * 32);
#pragma unroll
                for (int i = 0; i < 8; i++) {
                    float4 v = src4[i];
                    Au[base + i * 2]     = f2bf(v.x) | ((unsigned int)f2bf(v.y) << 16);
                    Au[base + i * 2 + 1] = f2bf(v.z) | ((unsigned int)f2bf(v.w) << 16);
                }
            } else {
#pragma unroll
                for (int i = 0; i < 16; i++) Au[base + i] = 0u;
            }
        }
        int sg = 0, sd = 0;
        if (ln < 16) {
            int row = rbase + ln;
            if (row < nv) { sg = gate[es[row]]; sd = ed[row]; }
        }
        __syncthreads();
        mlp3_scatter(wbmlp + (size_t)gi * 3 * 16384, hsw,
                     b1 + gi * HD, b2 + gi * HD, b3 + gi * HD,
                     SH, nv, sg, sd, msgN, rbase, ln, lc, quad);
    } else {
        // ===== tight push role (edges ls==d, ld==d+1): recompute hf =====
        if (d > 6) return;
        int b = bid - 384;
        int gi = b / 64;
        int tile = (b % 64) * 64;
        int glob = (d - 1) * 3 + gi;
        int cnt = tcnt[glob]; if (cnt > CAPT) cnt = CAPT;
        if (tile >= cnt) return;
        int nv = min(64, cnt - tile);
        const int* es = tsrc + glob * CAPT + tile;
        const int* ed = tdst + glob * CAPT + tile;

        for (int i = tid; i < 6 * 132; i += NTHR) {
            int t = i / 132, c = i % 132;
            hsw[i] = (c < HD) ? hsW1[(gi * 6 + t) * HD + c] : 0.f;
        }
        // stage msgN[src] + zfold -> bf16 (src is a level-d node; complete)
        {
            int row = rbase + (ln >> 2), q = ln & 3;
            int nrow = (row < nv) ? es[row] : -1;
            unsigned int* Mu = (unsigned int*)SH;
            int base = (row * AP + q * 32) >> 1;
            if (nrow >= 0) {
                int sgi = gi_of(gate[nrow]);   // src's OWN type selects its GRU
                const f32x4* m4 = (const f32x4*)(msgN + (size_t)nrow * HD + q * 32);
                const int* zc = zcntN + (size_t)nrow * 8;
                const f32x4* zt4 = (const f32x4*)ztab;
                f32x4 acc[8];
#pragma unroll
                for (int i = 0; i < 8; i++) acc[i] = m4[i];
#pragma unroll
                for (int t = 0; t < 6; t++) {
                    int ct = zc[t];
                    if (ct) {
                        float f = (float)ct;
                        const f32x4* z = zt4 + (sgi * 6 + t) * 32 + q * 8;
#pragma unroll
                        for (int i = 0; i < 8; i++) {
                            acc[i].x = fmaf(f, z[i].x, acc[i].x);
                            acc[i].y = fmaf(f, z[i].y, acc[i].y);
                            acc[i].z = fmaf(f, z[i].z, acc[i].z);
                            acc[i].w = fmaf(f, z[i].w, acc[i].w);
                        }
                    }
                }
#pragma unroll
                for (int i = 0; i < 8; i++) {
                    Mu[base + i * 2]     = f2bf(acc[i].x) | ((unsigned int)f2bf(acc[i].y) << 16);
                    Mu[base + i * 2 + 1] = f2bf(acc[i].z) | ((unsigned int)f2bf(acc[i].w) << 16);
                }
            } else {
#pragma unroll
                for (int i = 0; i < 16; i++) Mu[base + i] = 0u;
            }
        }
        int sg = 0, sd = 0, sgg = 0;
        if (ln < 16) {
            int row = rbase + ln;
            if (row < nv) {
                int s = es[row];
                sg = gate[s];
                sgg = gi_of(sg);   // src GRU variant (always >= 0 for tight)
                sd = ed[row];
            }
        }
        __syncthreads();

        // GRU recompute, SEQUENTIAL over the 3 weight variants (low VGPR):
        // shared A-frags in registers; each row written once by its variant.
        {
            bf16x8 af[4];
#pragma unroll
            for (int kc = 0; kc < 4; kc++)
                af[kc] = *(bf16x8*)&SH[(rbase + lc) * AP + kc * 32 + quad * 8];
            for (int g = 0; g < 3; g++) {
                if (__ballot(ln < 16 && sgg == g) == 0ULL) continue;
                const unsigned short* WB = wbih + (size_t)g * 49152;
                for (int nt = 0; nt < 8; nt++) {
                    f32x4 aR = {0.f, 0.f, 0.f, 0.f};
                    f32x4 aZ = {0.f, 0.f, 0.f, 0.f};
                    f32x4 aN = {0.f, 0.f, 0.f, 0.f};
#pragma unroll
                    for (int kc = 0; kc < 4; kc++) {
                        bf16x8 bR = *(const bf16x8*)&WB[(((nt)      * 4 + kc) * 64 + ln) * 8];
                        bf16x8 bZ = *(const bf16x8*)&WB[(((nt + 8)  * 4 + kc) * 64 + ln) * 8];
                        bf16x8 bN = *(const bf16x8*)&WB[(((nt + 16) * 4 + kc) * 64 + ln) * 8];
                        aR = __builtin_amdgcn_mfma_f32_16x16x32_bf16(af[kc], bR, aR, 0, 0, 0);
                        aZ = __builtin_amdgcn_mfma_f32_16x16x32_bf16(af[kc], bZ, aZ, 0, 0, 0);
                        aN = __builtin_amdgcn_mfma_f32_16x16x32_bf16(af[kc], bN, aN, 0, 0, 0);
                    }
                    int c = nt * 16 + lc;
                    float biR = bih[g * 384 + c],       bhR = bhh[g * 384 + c];
                    float biZ = bih[g * 384 + 128 + c], bhZ = bhh[g * 384 + 128 + c];
                    float biN = bih[g * 384 + 256 + c], bhN = bhh[g * 384 + 256 + c];
#pragma unroll
                    for (int r = 0; r < 4; r++) {
                        int row = rbase + quad * 4 + r;
                        int gg = __shfl(sgg, quad * 4 + r);
                        if (gg == g) {
                            float ir = aR[r] + biR + bhR;
                            float iz = aZ[r] + biZ + bhZ;
                            float inn = aN[r] + biN;
                            float rg = 1.f / (1.f + expf(-ir));
                            float zg = 1.f / (1.f + expf(-iz));
                            float nst = tanhf(inn + rg * bhN);
                            SH[row * AP + c] = f2bf((1.f - zg) * nst);
                        }
                    }
                }
            }
        }
        mlp3_scatter(wbmlp + (size_t)gi * 3 * 16384, hsw,
                     b1 + gi * HD, b2 + gi * HD, b3 + gi * HD,
                     SH, nv, sg, sd, msgN, rbase, ln, lc, quad);
    }
}

extern "C" void kernel_launch(void* const* d_in, const int* in_sizes, int n_in,
                              void* d_out, int out_size, void* d_ws, size_t ws_size,
                              hipStream_t stream) {
    const int* gate = (const int*)d_in[0];
    const int* lvl  = (const int*)d_in[1];
    const int* ei   = (const int*)d_in[2];
    const float* Ws   = (const float*)d_in[3];
    const float* Wt   = (const float*)d_in[4];
    const float* hs_W = (const float*)d_in[5];
    const float* hs_b = (const float*)d_in[6];
    const float* w1 = (const float*)d_in[7];
    const float* b1 = (const float*)d_in[8];
    const float* w2 = (const float*)d_in[9];
    const float* b2 = (const float*)d_in[10];
    const float* w3 = (const float*)d_in[11];
    const float* b3 = (const float*)d_in[12];
    const float* wih = (const float*)d_in[13];
    // d_in[14] = gru_whh: unused (h_old provably zero for every updated node)
    const float* bih = (const float*)d_in[15];
    const float* bhh = (const float*)d_in[16];
    float* out = (float*)d_out;
    char* ws = (char*)d_ws;

    int*   ncnt    = (int*)(ws + OFF_CNT);
    int*   scnt    = (int*)(ws + OFF_SCNT);
    int*   tcnt    = (int*)(ws + OFF_TCNT);
    int*   zcntN   = (int*)(ws + OFF_ZCNTN);
    float* msgN    = (float*)(ws + OFF_MSGN);
    float* hs_type = (float*)(ws + OFF_HSTYPE);
    float* hsW1    = (float*)(ws + OFF_HSW1);
    float* ztab    = (float*)(ws + OFF_ZTAB);
    unsigned short* wbmlp = (unsigned short*)(ws + OFF_WBMLP);
    unsigned short* wbih  = (unsigned short*)(ws + OFF_WBIH);
    int*   nlist   = (int*)(ws + OFF_NLIST);
    int*   ssrc    = (int*)(ws + OFF_SSRC);
    int*   sdst    = (int*)(ws + OFF_SDST);
    int*   tsrc    = (int*)(ws + OFF_TSRC);
    int*   tdst    = (int*)(ws + OFF_TDST);

    hipMemsetAsync(ws, 0, MEMSET_BYTES, stream);

    prep_a_kernel<<<128, NTHR, 0, stream>>>(Ws, Wt, hs_W, hs_b,
                                            w1, b1, w2, b2, w3, b3, wih,
                                            hs_type, hsW1, ztab, wbmlp, wbih);
    prep_b_kernel<<<1024, NTHR, 0, stream>>>(gate, lvl, ei, hs_type, out, msgN,
                                             ncnt, nlist, scnt, ssrc, sdst,
                                             tcnt, tsrc, tdst, zcntN);

    for (int l = 1; l < 8; l++) {
        level_kernel<<<576, NTHR, 0, stream>>>(
            l, gate, out, hsW1, ztab, wbmlp, wbih,
            b1, b2, b3, bih, bhh, ncnt, nlist, scnt, ssrc, sdst,
            tcnt, tsrc, tdst, zcntN, msgN);
    }
}

// Round 10
// 426.849 us; speedup vs baseline: 1.3523x; 1.3523x over previous
//
#include <hip/hip_runtime.h>
#include <math.h>

#define NN 100000
#define NE 200000
#define HD 128
#define CAPN 4096
#define CAPE 4096
#define NGROUP 21
#define AP 136             // bf16 LDS row pitch (shorts)
#define NTHR 256           // prep block size
#define LTHR 128           // msg/gru block size (2 waves, 32-row tiles)

typedef short bf16x8 __attribute__((ext_vector_type(8)));
typedef float f32x4 __attribute__((ext_vector_type(4)));

// workspace byte offsets; [0, MEMSET_BYTES) zeroed each launch
#define OFF_NCNT   0           // 21 ints
#define OFF_ECNT   128         // 21 ints (live edges per group)
#define OFF_ZCNT   1024        // 21*4096*8 ints (dead-edge counts per dst slot, src gate)
#define OFF_MSG    2753536     // 21*4096*128 f32 compact per-level msg buffers
#define MEMSET_BYTES 46793728
#define OFF_HSTYPE 46793728    // 6*128 f32
#define OFF_HSW1   46796800    // 3*6*128 f32
#define OFF_ZTAB   46806016    // 3*6*128 f32
#define OFF_WBMLP  46815232    // 3*3*16384 bf16 swizzled B-frags
#define OFF_WBIH   47110144    // 3*49152 bf16 swizzled B-frags
#define OFF_NLIST  47405056    // 21*4096 ints
#define OFF_NSLOT  47749120    // NN ints
#define OFF_ESRC   48149120    // 21*4096 ints (live: src node)
#define OFF_EDSL   48493184    // 21*4096 ints (live: dst slot)

#define SWTOT (3 * 3 * 16384 + 3 * 49152)

__device__ __forceinline__ int gi_of(int g) {
    return (g == 3) ? 0 : (g == 2) ? 1 : (g == 5) ? 2 : -1;
}

__device__ __forceinline__ unsigned short f2bf(float f) {
    unsigned int u = __float_as_uint(f);
    u += 0x7FFF + ((u >> 16) & 1);   // RNE
    return (unsigned short)(u >> 16);
}

// ---------------------------------------------------------------------------
// prep1: block 0 -> hs_type + hsW1; blocks 1..18 -> ztab (dead-edge msg);
// blocks 19+ -> weight swizzle + group_nodes.
// ---------------------------------------------------------------------------
__global__ __launch_bounds__(NTHR) void prep1_kernel(
    const int* __restrict__ gate, const int* __restrict__ lvl,
    const float* __restrict__ Ws, const float* __restrict__ Wt,
    const float* __restrict__ hs_W, const float* __restrict__ hs_b,
    const float* __restrict__ w1, const float* __restrict__ b1,
    const float* __restrict__ w2, const float* __restrict__ b2,
    const float* __restrict__ w3, const float* __restrict__ b3,
    const float* __restrict__ wih,
    float* __restrict__ hs_type, float* __restrict__ hsW1,
    float* __restrict__ ztab,
    unsigned short* __restrict__ wbmlp, unsigned short* __restrict__ wbih,
    int* __restrict__ ncnt, int* __restrict__ nlist, int* __restrict__ nslot) {
    __shared__ float lht[6 * HD];
    __shared__ float s0[HD], s1[HD], s2[HD];
    __shared__ int lcnt[NGROUP], lbase[NGROUP];
    const int bid = blockIdx.x, tid = threadIdx.x;

    if (bid == 0) {
        for (int idx = tid; idx < 6 * HD; idx += NTHR) {
            int t = idx >> 7, c = idx & 127;
            float acc = hs_b[c];
            for (int k = 0; k < HD; k++) acc = fmaf(Ws[t * HD + k], hs_W[k * HD + c], acc);
            for (int k = 0; k < HD; k++) acc = fmaf(Wt[t * HD + k], hs_W[(HD + k) * HD + c], acc);
            lht[idx] = acc;
            hs_type[idx] = acc;
        }
        __syncthreads();
        for (int idx = tid; idx < 3 * 6 * HD; idx += NTHR) {
            int gi = idx / (6 * HD);
            int t = (idx >> 7) % 6;
            int c = idx & 127;
            const float* w = w1 + gi * (2 * HD * HD);  // top half rows 0..127
            float acc = 0.f;
            for (int k = 0; k < HD; k++) acc = fmaf(lht[t * HD + k], w[k * HD + c], acc);
            hsW1[idx] = acc;
        }
    } else if (bid <= 18) {
        // ztab[gi][t] = MLP_gi([hs_type[t], 0])
        int gi = (bid - 1) / 6, t = (bid - 1) % 6;
        int c = tid;
        if (c < HD) {
            float acc = hs_b[c];
            for (int k = 0; k < HD; k++) acc = fmaf(Ws[t * HD + k], hs_W[k * HD + c], acc);
            for (int k = 0; k < HD; k++) acc = fmaf(Wt[t * HD + k], hs_W[(HD + k) * HD + c], acc);
            s0[c] = acc;
        }
        __syncthreads();
        if (c < HD) {
            const float* w = w1 + gi * (2 * HD * HD);
            float acc = b1[gi * HD + c];
            for (int k = 0; k < HD; k++) acc = fmaf(s0[k], w[k * HD + c], acc);
            s1[c] = fmaxf(acc, 0.f);
        }
        __syncthreads();
        if (c < HD) {
            const float* w = w2 + gi * (HD * HD);
            float acc = b2[gi * HD + c];
            for (int k = 0; k < HD; k++) acc = fmaf(s1[k], w[k * HD + c], acc);
            s2[c] = fmaxf(acc, 0.f);
        }
        __syncthreads();
        if (c < HD) {
            const float* w = w3 + gi * (HD * HD);
            float acc = b3[gi * HD + c];
            for (int k = 0; k < HD; k++) acc = fmaf(s2[k], w[k * HD + c], acc);
            ztab[(gi * 6 + t) * HD + c] = acc;
        }
    } else {
        const int nb = gridDim.x - 19;
        const int wb = bid - 19;
        for (int id = wb * NTHR + tid; id < SWTOT; id += nb * NTHR) {
            if (id < 3 * 3 * 16384) {
                int gi = id / 49152;
                int rem = id % 49152;
                int layer = rem / 16384;
                int e = rem % 16384;
                int k = e >> 7, n = e & 127;
                float v;
                if (layer == 0)      v = w1[gi * (2 * HD * HD) + (HD + k) * HD + n];
                else if (layer == 1) v = w2[gi * (HD * HD) + k * HD + n];
                else                 v = w3[gi * (HD * HD) + k * HD + n];
                int nt = n >> 4, kc = k >> 5, kq = (k >> 3) & 3, j = k & 7;
                int L = (kq << 4) | (n & 15);
                wbmlp[(size_t)(gi * 3 + layer) * 16384 + ((nt * 4 + kc) * 64 + L) * 8 + j] = f2bf(v);
            } else {
                int id2 = id - 3 * 3 * 16384;
                int gi = id2 / 49152;
                int e = id2 % 49152;
                int k = e / 384, n = e % 384;             // B[k][n] = wih[n][k]
                float v = wih[gi * (384 * HD) + n * HD + k];
                int nt = n >> 4, kc = k >> 5, kq = (k >> 3) & 3, j = k & 7;
                int L = (kq << 4) | (n & 15);
                wbih[(size_t)gi * 49152 + ((nt * 4 + kc) * 64 + L) * 8 + j] = f2bf(v);
            }
        }
        // group_nodes (LDS-aggregated)
        for (int base = wb * NTHR; base < NN; base += nb * NTHR) {
            if (tid < NGROUP) lcnt[tid] = 0;
            __syncthreads();
            int i = base + tid;
            int glob = -1, local = 0;
            if (i < NN) {
                int gi = gi_of(gate[i]);
                int l = lvl[i];
                if (gi >= 0 && l >= 1) {
                    glob = (l - 1) * 3 + gi;
                    local = atomicAdd(&lcnt[glob], 1);
                }
            }
            __syncthreads();
            if (tid < NGROUP) {
                int cc = lcnt[tid];
                lbase[tid] = cc ? atomicAdd(&ncnt[tid], cc) : 0;
            }
            __syncthreads();
            if (glob >= 0) {
                int slot = lbase[glob] + local;
                if (slot < CAPN) {
                    nlist[glob * CAPN + slot] = i;
                    nslot[i] = slot;
                }
            }
            __syncthreads();
        }
    }
}

// ---------------------------------------------------------------------------
// prep2: hs scatter (gather from hs_type — previous dispatch, no race) +
// group_edges with live/dead classification (dead -> one int atomic into
// zcnt[(glob,dslot,src_gate)]).  hf zeroing moved to an async fill.
// ---------------------------------------------------------------------------
__global__ __launch_bounds__(NTHR) void prep2_kernel(
    const int* __restrict__ gate, const int* __restrict__ lvl,
    const int* __restrict__ ei, const int* __restrict__ nslot,
    const float* __restrict__ hs_type, float* __restrict__ out,
    int* __restrict__ ecnt, int* __restrict__ esrc, int* __restrict__ edsl,
    int* __restrict__ zcnt) {
    __shared__ int lcnt[NGROUP], lbase[NGROUP];
    const int bid = blockIdx.x, tid = threadIdx.x;
    const int stride = gridDim.x * NTHR;

    const float4* ht4 = (const float4*)hs_type;
    float4* o4 = (float4*)out;
    for (int idx = bid * NTHR + tid; idx < NN * 32; idx += stride) {
        int i = idx >> 5, q = idx & 31;
        o4[idx] = ht4[gate[i] * 32 + q];
    }

    for (int base = 0; base < NE; base += stride) {
        if (tid < NGROUP) lcnt[tid] = 0;
        __syncthreads();
        int e = base + bid * NTHR + tid;
        int glob = -1, local = 0, s = 0, dsl = 0;
        if (e < NE) {
            int d = ei[NE + e];
            int gd = gi_of(gate[d]);
            int ld = lvl[d];
            if (gd >= 0 && ld >= 1) {
                int g = (ld - 1) * 3 + gd;
                s = ei[e];
                dsl = nslot[d];
                int gs = gate[s], ls = lvl[s];
                bool live = (gi_of(gs) >= 0) && (ls >= 1) && (ls < ld);
                if (live) {
                    glob = g;
                    local = atomicAdd(&lcnt[glob], 1);
                } else {
                    atomicAdd(&zcnt[((size_t)g * CAPN + dsl) * 8 + gs], 1);
                }
            }
        }
        __syncthreads();
        if (tid < NGROUP) {
            int cc = lcnt[tid];
            lbase[tid] = cc ? atomicAdd(&ecnt[tid], cc) : 0;
        }
        __syncthreads();
        if (glob >= 0) {
            int slot = lbase[glob] + local;
            if (slot < CAPE) {
                esrc[glob * CAPE + slot] = s;
                edsl[glob * CAPE + slot] = dsl;
            }
        }
        __syncthreads();
    }
}

// ---------------------------------------------------------------------------
// msg_kernel: 3-layer MFMA MLP over LIVE edges + atomic scatter into compact
// per-level msg rows. 32 edges/block (2 waves x 16-row bands), grid 3x128.
// ---------------------------------------------------------------------------
__global__ __launch_bounds__(LTHR) void msg_kernel(
    int level, const int* __restrict__ gate, const float* __restrict__ hf,
    const unsigned short* __restrict__ wbmlp,
    const float* __restrict__ b1, const float* __restrict__ b2,
    const float* __restrict__ b3, const float* __restrict__ hsW1,
    const int* __restrict__ ecnt, const int* __restrict__ esrc,
    const int* __restrict__ edsl, float* __restrict__ msg) {
    int gi = blockIdx.x >> 7;
    int tile = (blockIdx.x & 127) * 32;
    int glob = (level - 1) * 3 + gi;
    int cnt = ecnt[glob]; if (cnt > CAPE) cnt = CAPE;
    if (tile >= cnt) return;
    int nv = min(32, cnt - tile);

    __shared__ unsigned short SH[32 * AP];
    __shared__ float hsw[6 * 132];

    int tid = threadIdx.x;
    const int ln = tid & 63, wv = tid >> 6;
    const int lc = ln & 15, quad = ln >> 4;
    const int rbase = wv * 16;
    const int* es = esrc + glob * CAPE + tile;
    const int* ed = edsl + glob * CAPE + tile;
    float* msgL = msg + (size_t)glob * CAPN * HD;

    for (int i = tid; i < 6 * 132; i += LTHR) {
        int t = i / 132, c = i % 132;
        hsw[i] = (c < HD) ? hsW1[(gi * 6 + t) * HD + c] : 0.f;
    }
    // stage hf[src] tile (bf16), rows >= nv zeroed.  tids cover 32 rows,
    // each wave's tids write only its own band (wave-local).
    {
        int row = tid >> 2, q = tid & 3;
        unsigned int* Au = (unsigned int*)SH;
        int base = (row * AP + q * 32) >> 1;
        if (row < nv) {
            int s = es[row];
            const float4* src4 = (const float4*)(hf + (size_t)s * HD + q * 32);
#pragma unroll
            for (int i = 0; i < 8; i++) {
                float4 v = src4[i];
                Au[base + i * 2]     = f2bf(v.x) | ((unsigned int)f2bf(v.y) << 16);
                Au[base + i * 2 + 1] = f2bf(v.z) | ((unsigned int)f2bf(v.w) << 16);
            }
        } else {
#pragma unroll
            for (int i = 0; i < 16; i++) Au[base + i] = 0u;
        }
    }
    int sg = 0, sd = 0;
    if (ln < 16) {
        int row = rbase + ln;
        if (row < nv) { sg = gate[es[row]]; sd = ed[row]; }
    }
    __syncthreads();   // hsw visibility across waves

    const unsigned short* WB = wbmlp + (size_t)gi * 3 * 16384;
    float b1v[8], b2v[8], b3v[8];
#pragma unroll
    for (int nt = 0; nt < 8; nt++) {
        b1v[nt] = b1[gi * HD + nt * 16 + lc];
        b2v[nt] = b2[gi * HD + nt * 16 + lc];
        b3v[nt] = b3[gi * HD + nt * 16 + lc];
    }

    // layer 1: relu(hsW1[gate_src] + hf@W1bot + b1), in-place
    {
        bf16x8 af[4];
#pragma unroll
        for (int kc = 0; kc < 4; kc++)
            af[kc] = *(bf16x8*)&SH[(rbase + lc) * AP + kc * 32 + quad * 8];
        for (int nt = 0; nt < 8; nt++) {
            f32x4 acc = {0.f, 0.f, 0.f, 0.f};
#pragma unroll
            for (int kc = 0; kc < 4; kc++) {
                bf16x8 bf = *(const bf16x8*)&WB[((nt * 4 + kc) * 64 + ln) * 8];
                acc = __builtin_amdgcn_mfma_f32_16x16x32_bf16(af[kc], bf, acc, 0, 0, 0);
            }
#pragma unroll
            for (int r = 0; r < 4; r++) {
                int row = rbase + quad * 4 + r;
                int sgr = __shfl(sg, quad * 4 + r);
                float v = acc[r] + hsw[sgr * 132 + nt * 16 + lc] + b1v[nt];
                SH[row * AP + nt * 16 + lc] = f2bf(fmaxf(v, 0.f));
            }
        }
    }
    // layer 2
    {
        bf16x8 af[4];
#pragma unroll
        for (int kc = 0; kc < 4; kc++)
            af[kc] = *(bf16x8*)&SH[(rbase + lc) * AP + kc * 32 + quad * 8];
        for (int nt = 0; nt < 8; nt++) {
            f32x4 acc = {0.f, 0.f, 0.f, 0.f};
#pragma unroll
            for (int kc = 0; kc < 4; kc++) {
                bf16x8 bf = *(const bf16x8*)&WB[16384 + ((nt * 4 + kc) * 64 + ln) * 8];
                acc = __builtin_amdgcn_mfma_f32_16x16x32_bf16(af[kc], bf, acc, 0, 0, 0);
            }
#pragma unroll
            for (int r = 0; r < 4; r++) {
                int row = rbase + quad * 4 + r;
                SH[row * AP + nt * 16 + lc] = f2bf(fmaxf(acc[r] + b2v[nt], 0.f));
            }
        }
    }
    // layer 3 + scatter-add into compact msg rows
    {
        bf16x8 af[4];
#pragma unroll
        for (int kc = 0; kc < 4; kc++)
            af[kc] = *(bf16x8*)&SH[(rbase + lc) * AP + kc * 32 + quad * 8];
        for (int nt = 0; nt < 8; nt++) {
            f32x4 acc = {0.f, 0.f, 0.f, 0.f};
#pragma unroll
            for (int kc = 0; kc < 4; kc++) {
                bf16x8 bf = *(const bf16x8*)&WB[2 * 16384 + ((nt * 4 + kc) * 64 + ln) * 8];
                acc = __builtin_amdgcn_mfma_f32_16x16x32_bf16(af[kc], bf, acc, 0, 0, 0);
            }
#pragma unroll
            for (int r = 0; r < 4; r++) {
                int row = rbase + quad * 4 + r;
                if (row < nv) {
                    int sdr = __shfl(sd, quad * 4 + r);
                    atomicAdd(&msgL[(size_t)sdr * HD + nt * 16 + lc], acc[r] + b3v[nt]);
                }
            }
        }
    }
}

// ---------------------------------------------------------------------------
// gru_kernel: gin = (msg + zcnt*ztab) @ wih.T + bih ; gh = bhh (h_old == 0).
// Compact (coalesced) msg rows; zero-edge fold at staging. 32 nodes/block
// (2 waves), grid 3x128.  No block barrier (all LDS wave-local).
// ---------------------------------------------------------------------------
__global__ __launch_bounds__(LTHR) void gru_kernel(
    int level, const int* __restrict__ ncnt, const int* __restrict__ nlist,
    const unsigned short* __restrict__ wbih, const float* __restrict__ bih,
    const float* __restrict__ bhh, const float* __restrict__ msg,
    const int* __restrict__ zcnt, const float* __restrict__ ztab,
    float* __restrict__ out) {
    int gi = blockIdx.x >> 7;
    int tile = (blockIdx.x & 127) * 32;
    int glob = (level - 1) * 3 + gi;
    int cnt = ncnt[glob]; if (cnt > CAPN) cnt = CAPN;
    if (tile >= cnt) return;
    int nv = min(32, cnt - tile);

    __shared__ unsigned short SH[32 * AP];
    int tid = threadIdx.x;
    const int ln = tid & 63, wv = tid >> 6;
    const int lc = ln & 15, quad = ln >> 4;
    const int rbase = wv * 16;
    const float* msgL = msg + (size_t)glob * CAPN * HD;

    // stage msg row + zcnt*ztab fold -> bf16 (rows >= nv are all-zero: msg
    // memset + zcnt memset -> fold yields 0; harmless)
    {
        int row = tid >> 2, q = tid & 3;
        const f32x4* m4 = (const f32x4*)(msgL + (size_t)(tile + row) * HD + q * 32);
        const int* zc = zcnt + ((size_t)(glob * CAPN + tile + row)) * 8;
        const f32x4* zt4 = (const f32x4*)ztab;
        unsigned int* Mu = (unsigned int*)SH;
        int base = (row * AP + q * 32) >> 1;
        f32x4 acc[8];
#pragma unroll
        for (int i = 0; i < 8; i++) acc[i] = m4[i];
#pragma unroll
        for (int t = 0; t < 6; t++) {
            int ct = zc[t];
            if (ct) {
                float f = (float)ct;
                const f32x4* z = zt4 + (gi * 6 + t) * 32 + q * 8;
#pragma unroll
                for (int i = 0; i < 8; i++) {
                    acc[i].x = fmaf(f, z[i].x, acc[i].x);
                    acc[i].y = fmaf(f, z[i].y, acc[i].y);
                    acc[i].z = fmaf(f, z[i].z, acc[i].z);
                    acc[i].w = fmaf(f, z[i].w, acc[i].w);
                }
            }
        }
#pragma unroll
        for (int i = 0; i < 8; i++) {
            Mu[base + i * 2]     = f2bf(acc[i].x) | ((unsigned int)f2bf(acc[i].y) << 16);
            Mu[base + i * 2 + 1] = f2bf(acc[i].z) | ((unsigned int)f2bf(acc[i].w) << 16);
        }
    }
    int nd = -1;
    if (ln < 16) {
        int row = rbase + ln;
        nd = (row < nv) ? nlist[glob * CAPN + tile + row] : -1;
    }

    const unsigned short* WB = wbih + (size_t)gi * 49152;
    bf16x8 af[4];
#pragma unroll
    for (int kc = 0; kc < 4; kc++)
        af[kc] = *(bf16x8*)&SH[(rbase + lc) * AP + kc * 32 + quad * 8];

    float* hfout = out + (size_t)NN * HD;
    for (int nt = 0; nt < 8; nt++) {
        f32x4 aR = {0.f, 0.f, 0.f, 0.f};
        f32x4 aZ = {0.f, 0.f, 0.f, 0.f};
        f32x4 aN = {0.f, 0.f, 0.f, 0.f};
#pragma unroll
        for (int kc = 0; kc < 4; kc++) {
            bf16x8 bR = *(const bf16x8*)&WB[(((nt)      * 4 + kc) * 64 + ln) * 8];
            bf16x8 bZ = *(const bf16x8*)&WB[(((nt + 8)  * 4 + kc) * 64 + ln) * 8];
            bf16x8 bN = *(const bf16x8*)&WB[(((nt + 16) * 4 + kc) * 64 + ln) * 8];
            aR = __builtin_amdgcn_mfma_f32_16x16x32_bf16(af[kc], bR, aR, 0, 0, 0);
            aZ = __builtin_amdgcn_mfma_f32_16x16x32_bf16(af[kc], bZ, aZ, 0, 0, 0);
            aN = __builtin_amdgcn_mfma_f32_16x16x32_bf16(af[kc], bN, aN, 0, 0, 0);
        }
        int c = nt * 16 + lc;
        float biR = bih[gi * 384 + c],       bhR = bhh[gi * 384 + c];
        float biZ = bih[gi * 384 + 128 + c], bhZ = bhh[gi * 384 + 128 + c];
        float biN = bih[gi * 384 + 256 + c], bhN = bhh[gi * 384 + 256 + c];
#pragma unroll
        for (int r = 0; r < 4; r++) {
            int row = rbase + quad * 4 + r;
            int n = __shfl(nd, quad * 4 + r);
            if (n >= 0 && row < nv) {
                float ir = aR[r] + biR + bhR;
                float iz = aZ[r] + biZ + bhZ;
                float inn = aN[r] + biN;
                float rg = 1.f / (1.f + expf(-ir));
                float zg = 1.f / (1.f + expf(-iz));
                float nst = tanhf(inn + rg * bhN);
                hfout[(size_t)n * HD + c] = (1.f - zg) * nst;
            }
        }
    }
}

extern "C" void kernel_launch(void* const* d_in, const int* in_sizes, int n_in,
                              void* d_out, int out_size, void* d_ws, size_t ws_size,
                              hipStream_t stream) {
    const int* gate = (const int*)d_in[0];
    const int* lvl  = (const int*)d_in[1];
    const int* ei   = (const int*)d_in[2];
    const float* Ws   = (const float*)d_in[3];
    const float* Wt   = (const float*)d_in[4];
    const float* hs_W = (const float*)d_in[5];
    const float* hs_b = (const float*)d_in[6];
    const float* w1 = (const float*)d_in[7];
    const float* b1 = (const float*)d_in[8];
    const float* w2 = (const float*)d_in[9];
    const float* b2 = (const float*)d_in[10];
    const float* w3 = (const float*)d_in[11];
    const float* b3 = (const float*)d_in[12];
    const float* wih = (const float*)d_in[13];
    // d_in[14] = gru_whh: unused (h_old provably zero for every updated node)
    const float* bih = (const float*)d_in[15];
    const float* bhh = (const float*)d_in[16];
    float* out = (float*)d_out;
    char* ws = (char*)d_ws;

    int*   ncnt    = (int*)(ws + OFF_NCNT);
    int*   ecnt    = (int*)(ws + OFF_ECNT);
    int*   zcnt    = (int*)(ws + OFF_ZCNT);
    float* msg     = (float*)(ws + OFF_MSG);
    float* hs_type = (float*)(ws + OFF_HSTYPE);
    float* hsW1    = (float*)(ws + OFF_HSW1);
    float* ztab    = (float*)(ws + OFF_ZTAB);
    unsigned short* wbmlp = (unsigned short*)(ws + OFF_WBMLP);
    unsigned short* wbih  = (unsigned short*)(ws + OFF_WBIH);
    int*   nlist   = (int*)(ws + OFF_NLIST);
    int*   nslot   = (int*)(ws + OFF_NSLOT);
    int*   esrc    = (int*)(ws + OFF_ESRC);
    int*   edsl    = (int*)(ws + OFF_EDSL);

    // counters + zcnt + msg buffers zeroed by one fast runtime fill;
    // hf half of the output zeroed by a second fill (6.4 TB/s measured).
    hipMemsetAsync(ws, 0, MEMSET_BYTES, stream);
    hipMemsetAsync(out + (size_t)NN * HD, 0, (size_t)NN * HD * 4, stream);

    prep1_kernel<<<256, NTHR, 0, stream>>>(gate, lvl, Ws, Wt, hs_W, hs_b,
                                           w1, b1, w2, b2, w3, b3, wih,
                                           hs_type, hsW1, ztab, wbmlp, wbih,
                                           ncnt, nlist, nslot);
    prep2_kernel<<<1024, NTHR, 0, stream>>>(gate, lvl, ei, nslot, hs_type, out,
                                            ecnt, esrc, edsl, zcnt);

    const float* hf = out + (size_t)NN * HD;
    for (int l = 1; l < 8; l++) {
        if (l > 1)  // level 1 provably has zero live edges
            msg_kernel<<<3 * 128, LTHR, 0, stream>>>(l, gate, hf, wbmlp, b1, b2, b3,
                                                     hsW1, ecnt, esrc, edsl, msg);
        gru_kernel<<<3 * 128, LTHR, 0, stream>>>(l, ncnt, nlist, wbih, bih, bhh,
                                                 msg, zcnt, ztab, out);
    }
}